// Round 16
// baseline (433.671 us; speedup 1.0000x reference)
//
#include <hip/hip_runtime.h>
#include <hip/hip_bf16.h>
#include <hip/hip_fp16.h>
#include <cmath>

typedef unsigned short u16;
typedef unsigned long long ull;
typedef __attribute__((ext_vector_type(8))) short short8;
typedef __attribute__((ext_vector_type(4))) float f32x4;
typedef __attribute__((ext_vector_type(4))) unsigned short u16x4;

__device__ __forceinline__ u16 f2bf(float x) {
    unsigned u = __float_as_uint(x);
    u += 0x7fffu + ((u >> 16) & 1u);
    return (u16)(u >> 16);
}
__device__ __forceinline__ float bf2f(u16 b) {
    return __uint_as_float(((unsigned)b) << 16);
}

// sortable-u16 key <-> f16 bits (order-preserving map)
__device__ __forceinline__ unsigned h2key(unsigned hb) {
    return (hb & 0x8000u) ? (hb ^ 0xFFFFu) : (hb | 0x8000u);
}
__device__ __forceinline__ float key2f(unsigned k) {
    unsigned hb = (k & 0x8000u) ? (k ^ 0x8000u) : (k ^ 0xFFFFu);
    return __half2float(__ushort_as_half((unsigned short)hb));
}

// async global->LDS 16B per lane: dest = ldsbase + lane*16 (wave-uniform base)
typedef __attribute__((address_space(3))) unsigned int as3_uint;
typedef __attribute__((address_space(1))) unsigned int as1_uint;
__device__ __forceinline__ void gload_lds16(const u16* g, u16* l) {
    __builtin_amdgcn_global_load_lds(
        (as1_uint*)(unsigned long long)(const void*)g,
        (as3_uint*)(unsigned int)(unsigned long long)(const void*)l,
        16, 0, 0);
}

__device__ __forceinline__ float gelu_exact(float g) {
    return 0.5f * g * (1.f + erff(g * 0.70710678118654752f));
}

// ---------------- batched transpose+cast: w[K][N] f32 -> wt[N][K] bf16 --------
struct TBatch {
    const float* src[16];
    u16* dst[16];
    int K[16];
    int N[16];
    int start[17];
};

__global__ void k_transpose_cast_batch(TBatch tb) {
    __shared__ float tile[32][33];
    int t = blockIdx.x;
    int m = 0;
    while (t >= tb.start[m + 1]) ++m;
    int rel = t - tb.start[m];
    const int K = tb.K[m], N = tb.N[m];
    const int ntx = N >> 5;
    const int n0 = (rel % ntx) * 32, k0 = (rel / ntx) * 32;
    const float* __restrict__ in = tb.src[m];
    u16* __restrict__ out = tb.dst[m];
    int tx = threadIdx.x, ty = threadIdx.y;
#pragma unroll
    for (int j = 0; j < 4; ++j)
        tile[ty + j * 8][tx] = in[(size_t)(k0 + ty + j * 8) * N + n0 + tx];
    __syncthreads();
#pragma unroll
    for (int j = 0; j < 4; ++j)
        out[(size_t)(n0 + ty + j * 8) * K + k0 + tx] = f2bf(tile[tx][ty + j * 8]);
}

// -------- V transpose (bf16 in): in[b*256+k][stride] col coloff+d -> out[b][512][256]
__global__ void k_vtrans16(const u16* __restrict__ in, int stride, int coloff,
                           u16* __restrict__ out) {
    __shared__ int tile[32][33];
    int tx = threadIdx.x, ty = threadIdx.y;
    int d0 = blockIdx.x * 32, k0 = blockIdx.y * 32, b = blockIdx.z;
#pragma unroll
    for (int j = 0; j < 4; ++j)
        tile[ty + j * 8][tx] = in[(size_t)(b * 256 + k0 + ty + j * 8) * stride + coloff + d0 + tx];
    __syncthreads();
#pragma unroll
    for (int j = 0; j < 4; ++j)
        out[(size_t)(b * 512 + d0 + ty + j * 8) * 256 + k0 + tx] = (u16)tile[tx][ty + j * 8];
}

// ---------------- LayerNorm (fp32 in) -> bf16 out; float4-vectorized ----------
__global__ __launch_bounds__(256)
void k_ln_bf16(const float* __restrict__ in, const float* __restrict__ gam,
               const float* __restrict__ bet, u16* __restrict__ out, int F) {
    int lane = threadIdx.x & 63, w = threadIdx.x >> 6;
    int row = blockIdx.x * 4 + w;
    const int F4 = F >> 2;
    const float4* r4 = reinterpret_cast<const float4*>(in + (size_t)row * F);
    const float4* g4 = reinterpret_cast<const float4*>(gam);
    const float4* b4 = reinterpret_cast<const float4*>(bet);
    float s = 0.f, s2 = 0.f;
    for (int j = lane; j < F4; j += 64) {
        float4 v = r4[j];
        s += v.x + v.y + v.z + v.w;
        s2 += v.x * v.x + v.y * v.y + v.z * v.z + v.w * v.w;
    }
#pragma unroll
    for (int off = 32; off; off >>= 1) { s += __shfl_xor(s, off); s2 += __shfl_xor(s2, off); }
    float mean = s / F;
    float var  = s2 / F - mean * mean;
    float inv  = 1.f / sqrtf(var + 1e-5f);
    u16x4* o4 = reinterpret_cast<u16x4*>(out + (size_t)row * F);
    for (int j = lane; j < F4; j += 64) {
        float4 v = r4[j], gm = g4[j], bt = b4[j];
        u16x4 o;
        o[0] = f2bf((v.x - mean) * inv * gm.x + bt.x);
        o[1] = f2bf((v.y - mean) * inv * gm.y + bt.y);
        o[2] = f2bf((v.z - mean) * inv * gm.z + bt.z);
        o[3] = f2bf((v.w - mean) * inv * gm.w + bt.w);
        o4[j] = o;
    }
}

// ------- bf16 MFMA GEMM (templated tile): C[M,N] = A[M,K] @ Bt[N,K]^T ---------
// Chunked XCD swizzle (requires gridDim.x*gridDim.y % 8 == 0).
template <int BM, int BN>
__global__ __launch_bounds__(256)
void gemm_bt(const u16* __restrict__ A, const u16* __restrict__ Bt,
             const float* __restrict__ bias, const float* __restrict__ res,
             float* __restrict__ out32, u16* __restrict__ out16,
             int M, int N, int K) {
    constexpr int WM = BM / 2, WN = BN / 2, FM = WM / 16, FN = WN / 16;
    __shared__ __align__(16) u16 As[BM * 32];
    __shared__ __align__(16) u16 Bs[BN * 32];
    const int tid = threadIdx.x;
    const int lane = tid & 63;
    const int wid = tid >> 6;
    const int wr = wid >> 1, wc = wid & 1;
    const int nwg = gridDim.x * gridDim.y;
    int lin = blockIdx.y * gridDim.x + blockIdx.x;
    lin = (lin & 7) * (nwg >> 3) + (lin >> 3);   // contiguous chunk per XCD
    const int m0 = (lin / gridDim.x) * BM, n0 = (lin % gridDim.x) * BN;
    const int r16 = lane & 15;
    const int g8  = (lane >> 4) * 8;
    const int w16 = wid * 16;
    const int ln4 = lane >> 2;
    const int cb8 = (lane & 3) * 8;

    const f32x4 zero4 = {0.f, 0.f, 0.f, 0.f};
    f32x4 acc[FM][FN];
#pragma unroll
    for (int m = 0; m < FM; ++m)
#pragma unroll
        for (int n = 0; n < FN; ++n) acc[m][n] = zero4;

    for (int k0 = 0; k0 < K; k0 += 32) {
#pragma unroll
        for (int p = 0; p < BM / 64; ++p) {
            const int rb = p * 64 + w16;
            gload_lds16(A + (size_t)(m0 + rb + ln4) * K + k0 + cb8, &As[rb * 32]);
        }
#pragma unroll
        for (int p = 0; p < BN / 64; ++p) {
            const int rb = p * 64 + w16;
            gload_lds16(Bt + (size_t)(n0 + rb + ln4) * K + k0 + cb8, &Bs[rb * 32]);
        }
        __syncthreads();
        short8 af[FM], bfr[FN];
#pragma unroll
        for (int m = 0; m < FM; ++m)
            af[m] = *reinterpret_cast<const short8*>(&As[(wr * WM + m * 16 + r16) * 32 + g8]);
#pragma unroll
        for (int n = 0; n < FN; ++n)
            bfr[n] = *reinterpret_cast<const short8*>(&Bs[(wc * WN + n * 16 + r16) * 32 + g8]);
#pragma unroll
        for (int m = 0; m < FM; ++m)
#pragma unroll
            for (int n = 0; n < FN; ++n)
                acc[m][n] = __builtin_amdgcn_mfma_f32_16x16x32_bf16(af[m], bfr[n], acc[m][n], 0, 0, 0);
        __syncthreads();
    }

    const int rg = (lane >> 4) * 4;
#pragma unroll
    for (int m = 0; m < FM; ++m) {
#pragma unroll
        for (int n = 0; n < FN; ++n) {
#pragma unroll
            for (int j = 0; j < 4; ++j) {
                int row = m0 + wr * WM + m * 16 + rg + j;
                int col = n0 + wc * WN + n * 16 + r16;
                float v = acc[m][n][j];
                if (bias) v += bias[col];
                size_t off = (size_t)row * N + col;
                if (res) v += res[off];
                if (out32) out32[off] = v;
                if (out16) out16[off] = f2bf(v);
            }
        }
    }
}

// ---- GEGLU-fused GEMM: out[M,Nh] = (A@Wa^T + ba) * gelu(A@Wg^T + bg) ---------
template <int BM>
__global__ __launch_bounds__(256)
void gemm_geglu(const u16* __restrict__ A, const u16* __restrict__ Bt,
                const float* __restrict__ bias, u16* __restrict__ out16,
                int M, int Nh, int K) {
    constexpr int WM = BM / 2, FM = WM / 16;
    __shared__ __align__(16) u16 As[BM * 32];
    __shared__ __align__(16) u16 Bs[128 * 32];
    const int tid = threadIdx.x;
    const int lane = tid & 63;
    const int wid = tid >> 6;
    const int wr = wid >> 1, wc = wid & 1;
    const int nwg = gridDim.x * gridDim.y;
    int lin = blockIdx.y * gridDim.x + blockIdx.x;
    lin = (lin & 7) * (nwg >> 3) + (lin >> 3);
    const int m0 = (lin / gridDim.x) * BM, n0 = (lin % gridDim.x) * 64;
    const int r16 = lane & 15;
    const int g8  = (lane >> 4) * 8;
    const int w16 = wid * 16;
    const int ln4 = lane >> 2;
    const int cb8 = (lane & 3) * 8;

    const f32x4 zero4 = {0.f, 0.f, 0.f, 0.f};
    f32x4 acc_a[FM][2], acc_g[FM][2];
#pragma unroll
    for (int m = 0; m < FM; ++m)
#pragma unroll
        for (int n = 0; n < 2; ++n) { acc_a[m][n] = zero4; acc_g[m][n] = zero4; }

    for (int k0 = 0; k0 < K; k0 += 32) {
#pragma unroll
        for (int p = 0; p < BM / 64; ++p) {
            const int rb = p * 64 + w16;
            gload_lds16(A + (size_t)(m0 + rb + ln4) * K + k0 + cb8, &As[rb * 32]);
        }
        gload_lds16(Bt + (size_t)(n0 + w16 + ln4) * K + k0 + cb8, &Bs[w16 * 32]);
        gload_lds16(Bt + (size_t)(Nh + n0 + w16 + ln4) * K + k0 + cb8, &Bs[(64 + w16) * 32]);
        __syncthreads();
        short8 af[FM], ba[2], bg[2];
#pragma unroll
        for (int m = 0; m < FM; ++m)
            af[m] = *reinterpret_cast<const short8*>(&As[(wr * WM + m * 16 + r16) * 32 + g8]);
#pragma unroll
        for (int n = 0; n < 2; ++n) {
            ba[n] = *reinterpret_cast<const short8*>(&Bs[(wc * 32 + n * 16 + r16) * 32 + g8]);
            bg[n] = *reinterpret_cast<const short8*>(&Bs[(64 + wc * 32 + n * 16 + r16) * 32 + g8]);
        }
#pragma unroll
        for (int m = 0; m < FM; ++m)
#pragma unroll
            for (int n = 0; n < 2; ++n) {
                acc_a[m][n] = __builtin_amdgcn_mfma_f32_16x16x32_bf16(af[m], ba[n], acc_a[m][n], 0, 0, 0);
                acc_g[m][n] = __builtin_amdgcn_mfma_f32_16x16x32_bf16(af[m], bg[n], acc_g[m][n], 0, 0, 0);
            }
        __syncthreads();
    }

    const int rg = (lane >> 4) * 4;
#pragma unroll
    for (int m = 0; m < FM; ++m) {
#pragma unroll
        for (int n = 0; n < 2; ++n) {
#pragma unroll
            for (int j = 0; j < 4; ++j) {
                int row = m0 + wr * WM + m * 16 + rg + j;
                int col = n0 + wc * 32 + n * 16 + r16;
                float a = acc_a[m][n][j] + bias[col];
                float g = acc_g[m][n][j] + bias[Nh + col];
                out16[(size_t)row * Nh + col] = f2bf(a * gelu_exact(g));
            }
        }
    }
}

// ---------------- MFMA SDPA attention, 256 keys, 8 heads, dh=64 ----------------
// XCD swizzle: h = bid&7 pins each head's K/V panel to one XCD L2.
__global__ __launch_bounds__(256)
void k_attn_mfma(const u16* __restrict__ Qb, int sq, const u16* __restrict__ Kb,
                 int sk, const u16* __restrict__ VT, u16* __restrict__ out, int NQ) {
    __shared__ float sc[16][268];
    __shared__ u16   pb[16][268];
    const int tid = threadIdx.x, lane = tid & 63, w = tid >> 6;
    const int nqb = NQ >> 4;
    const int h = blockIdx.x & 7;
    const int rest = blockIdx.x >> 3;
    const int b = rest / nqb;
    const int q0 = (rest % nqb) << 4;
    const int r16 = lane & 15, g8 = (lane >> 4) * 8, rq = (lane >> 4) * 4;

    const size_t qrow = ((size_t)(b * NQ + q0 + r16)) * sq + h * 64;
    const short8 af0 = *reinterpret_cast<const short8*>(Qb + qrow + g8);
    const short8 af1 = *reinterpret_cast<const short8*>(Qb + qrow + 32 + g8);
    const u16* kb = Kb + (size_t)b * 256 * sk + h * 64;
    const f32x4 zero4 = {0.f, 0.f, 0.f, 0.f};
#pragma unroll
    for (int t = 0; t < 4; ++t) {
        const size_t krow = (size_t)(t * 64 + w * 16 + r16) * sk;
        const short8 bf0 = *reinterpret_cast<const short8*>(kb + krow + g8);
        const short8 bf1 = *reinterpret_cast<const short8*>(kb + krow + 32 + g8);
        f32x4 acc = __builtin_amdgcn_mfma_f32_16x16x32_bf16(af0, bf0, zero4, 0, 0, 0);
        acc = __builtin_amdgcn_mfma_f32_16x16x32_bf16(af1, bf1, acc, 0, 0, 0);
        const int col = t * 64 + w * 16 + r16;
#pragma unroll
        for (int j = 0; j < 4; ++j) sc[rq + j][col] = acc[j] * 0.125f;
    }
    __syncthreads();
#pragma unroll
    for (int qi = 0; qi < 4; ++qi) {
        const int q = w * 4 + qi;
        float4 v = *reinterpret_cast<const float4*>(&sc[q][lane * 4]);
        float m = fmaxf(fmaxf(v.x, v.y), fmaxf(v.z, v.w));
#pragma unroll
        for (int off = 32; off; off >>= 1) m = fmaxf(m, __shfl_xor(m, off));
        float e0 = expf(v.x - m), e1 = expf(v.y - m), e2 = expf(v.z - m), e3 = expf(v.w - m);
        float sum = e0 + e1 + e2 + e3;
#pragma unroll
        for (int off = 32; off; off >>= 1) sum += __shfl_xor(sum, off);
        float inv = 1.f / sum;
        u16x4 p4;
        p4[0] = f2bf(e0 * inv); p4[1] = f2bf(e1 * inv);
        p4[2] = f2bf(e2 * inv); p4[3] = f2bf(e3 * inv);
        *reinterpret_cast<u16x4*>(&pb[q][lane * 4]) = p4;
    }
    __syncthreads();
    f32x4 o = zero4;
    const u16* vt = VT + ((size_t)(b * 512 + h * 64 + w * 16 + r16)) * 256;
#pragma unroll
    for (int kk = 0; kk < 8; ++kk) {
        const short8 pa = *reinterpret_cast<const short8*>(&pb[r16][kk * 32 + g8]);
        const short8 vv = *reinterpret_cast<const short8*>(vt + kk * 32 + g8);
        o = __builtin_amdgcn_mfma_f32_16x16x32_bf16(pa, vv, o, 0, 0, 0);
    }
#pragma unroll
    for (int j = 0; j < 4; ++j)
        out[((size_t)(b * NQ + q0 + rq + j)) * 512 + h * 64 + w * 16 + r16] = f2bf(o[j]);
}

// ---- topk scores GEMM: keys[bh][q][k] = sortable_u16(f16(QK^T * 0.125)) ------
__global__ __launch_bounds__(256)
void gemm_scores(const u16* __restrict__ QKV, u16* __restrict__ keys) {
    __shared__ __align__(16) u16 As[2][128 * 32];
    __shared__ __align__(16) u16 Bs[2][128 * 32];
    const int tid = threadIdx.x;
    const int lane = tid & 63;
    const int wid = tid >> 6;
    const int wr = wid >> 1, wc = wid & 1;
    int lin = blockIdx.x;                       // 5184 = 16 * 324
    lin = (lin & 7) * 648 + (lin >> 3);
    const int bh = lin / 324;
    const int rel = lin % 324;
    const int m0 = (rel / 18) * 128, n0 = (rel % 18) * 128;
    const int b = bh >> 3, h = bh & 7;
    const u16* Qb = QKV + (size_t)b * 2304 * 1536 + h * 64;   // rows stride 1536
    const u16* Kb = Qb + 512;
    const int r16 = lane & 15;
    const int g8  = (lane >> 4) * 8;
    const int w16 = wid * 16;
    const int ln4 = lane >> 2;
    const int cb8 = (lane & 3) * 8;

#pragma unroll
    for (int kk = 0; kk < 2; ++kk) {
#pragma unroll
        for (int p = 0; p < 2; ++p) {
            const int rb = p * 64 + w16;
            gload_lds16(Qb + (size_t)(m0 + rb + ln4) * 1536 + kk * 32 + cb8, &As[kk][rb * 32]);
            gload_lds16(Kb + (size_t)(n0 + rb + ln4) * 1536 + kk * 32 + cb8, &Bs[kk][rb * 32]);
        }
    }
    __syncthreads();

    const f32x4 zero4 = {0.f, 0.f, 0.f, 0.f};
    f32x4 acc[4][4];
#pragma unroll
    for (int m = 0; m < 4; ++m)
#pragma unroll
        for (int n = 0; n < 4; ++n) acc[m][n] = zero4;

    short8 af[2][4], bfr[2][4];
#pragma unroll
    for (int kk = 0; kk < 2; ++kk)
#pragma unroll
        for (int m = 0; m < 4; ++m) {
            af[kk][m] = *reinterpret_cast<const short8*>(&As[kk][(wr * 64 + m * 16 + r16) * 32 + g8]);
            bfr[kk][m] = *reinterpret_cast<const short8*>(&Bs[kk][(wc * 64 + m * 16 + r16) * 32 + g8]);
        }
#pragma unroll
    for (int kk = 0; kk < 2; ++kk)
#pragma unroll
        for (int m = 0; m < 4; ++m)
#pragma unroll
            for (int n = 0; n < 4; ++n)
                acc[m][n] = __builtin_amdgcn_mfma_f32_16x16x32_bf16(af[kk][m], bfr[kk][n], acc[m][n], 0, 0, 0);

    u16* kout = keys + (size_t)bh * 2304 * 2304;
    const int rg = (lane >> 4) * 4;
#pragma unroll
    for (int m = 0; m < 4; ++m) {
#pragma unroll
        for (int n = 0; n < 4; ++n) {
#pragma unroll
            for (int j = 0; j < 4; ++j) {
                int row = m0 + wr * 64 + m * 16 + rg + j;
                int col = n0 + wc * 64 + n * 16 + r16;
                unsigned hb = __half_as_ushort(__float2half(acc[m][n][j] * 0.125f));
                kout[(size_t)row * 2304 + col] = (u16)h2key(hb);
            }
        }
    }
}

// ---- per-query tail: strict extraction + tie + softmax + PV (macro keeps
// the register key array in registers; textual substitution, no scratch) ------
#define SEL_TAIL(KP, THR, QIDX, SLOT)                                           \
    {                                                                           \
        const unsigned tp = (THR) * 0x10001u;                                   \
        _Pragma("unroll")                                                       \
        for (int i = 0; i < 18; ++i) {                                          \
            unsigned s;                                                         \
            asm("v_pk_sub_u16 %0, %1, %2 clamp" : "=v"(s) : "v"(KP[i]), "v"(tp)); \
            if (s) {                                                            \
                const unsigned klo = KP[i] & 0xFFFFu, khi = KP[i] >> 16;        \
                const int gbase = (i >> 1) * 256 + lane * 4 + (i & 1) * 2;      \
                if (klo > (THR)) {                                              \
                    unsigned pos = atomicAdd(&cnt[SLOT], 1u);                   \
                    ilist[SLOT][pos] = gbase; wlist[SLOT][pos] = key2f(klo);    \
                }                                                               \
                if (khi > (THR)) {                                              \
                    unsigned pos = atomicAdd(&cnt[SLOT], 1u);                   \
                    ilist[SLOT][pos] = gbase + 1; wlist[SLOT][pos] = key2f(khi); \
                }                                                               \
            }                                                                   \
        }                                                                       \
        const int tot = (int)cnt[SLOT];                                         \
        const int r = 32 - tot;                                                 \
        if (r > 0) {                                                            \
            const float tv = key2f(THR);                                        \
            int t2 = 0;                                                         \
            _Pragma("unroll")                                                   \
            for (int j = 0; j < 9; ++j) {                                       \
                if (t2 < r) {                                                   \
                    const unsigned x = KP[2 * j], y = KP[2 * j + 1];            \
                    const unsigned ka = x & 0xFFFFu, kb2 = x >> 16;             \
                    const unsigned kc = y & 0xFFFFu, kd = y >> 16;              \
                    const ull e0 = __ballot(ka == (THR));                       \
                    const ull e1 = __ballot(kb2 == (THR));                      \
                    const ull e2 = __ballot(kc == (THR));                       \
                    const ull e3 = __ballot(kd == (THR));                       \
                    const int base = (int)__popcll(e0 & ltm) + (int)__popcll(e1 & ltm) + \
                                     (int)__popcll(e2 & ltm) + (int)__popcll(e3 & ltm); \
                    const int b0 = (int)((e0 >> lane) & 1ull);                  \
                    const int b1 = b0 + (int)((e1 >> lane) & 1ull);             \
                    const int b2 = b1 + (int)((e2 >> lane) & 1ull);             \
                    if (ka == (THR)) { int pos = t2 + base;                     \
                        if (pos < r) { ilist[SLOT][tot + pos] = j * 256 + lane * 4 + 0; wlist[SLOT][tot + pos] = tv; } } \
                    if (kb2 == (THR)) { int pos = t2 + base + b0;               \
                        if (pos < r) { ilist[SLOT][tot + pos] = j * 256 + lane * 4 + 1; wlist[SLOT][tot + pos] = tv; } } \
                    if (kc == (THR)) { int pos = t2 + base + b1;                \
                        if (pos < r) { ilist[SLOT][tot + pos] = j * 256 + lane * 4 + 2; wlist[SLOT][tot + pos] = tv; } } \
                    if (kd == (THR)) { int pos = t2 + base + b2;                \
                        if (pos < r) { ilist[SLOT][tot + pos] = j * 256 + lane * 4 + 3; wlist[SLOT][tot + pos] = tv; } } \
                    t2 += (int)__popcll(e0) + (int)__popcll(e1) +               \
                          (int)__popcll(e2) + (int)__popcll(e3);                \
                }                                                               \
            }                                                                   \
        }                                                                       \
        float wv = (lane < 32) ? wlist[SLOT][lane] : -3.0e38f;                  \
        float mf = wv;                                                          \
        _Pragma("unroll")                                                       \
        for (int off = 32; off; off >>= 1) mf = fmaxf(mf, __shfl_xor(mf, off)); \
        float e = (lane < 32) ? expf(wv - mf) : 0.f;                            \
        float sum = e;                                                          \
        _Pragma("unroll")                                                       \
        for (int off = 32; off; off >>= 1) sum += __shfl_xor(sum, off);         \
        if (lane < 32) wlist[SLOT][lane] = e / sum;                             \
        const u16* vb = QKV + (size_t)b * 2304 * 1536 + 1024 + h * 64 + lane;   \
        u16 vr[32];                                                             \
        _Pragma("unroll")                                                       \
        for (int i = 0; i < 32; ++i)                                            \
            vr[i] = vb[(size_t)ilist[SLOT][i] * 1536];                          \
        float o = 0.f;                                                          \
        _Pragma("unroll")                                                       \
        for (int i = 0; i < 32; ++i)                                            \
            o += wlist[SLOT][i] * bf2f(vr[i]);                                  \
        out[((size_t)(b * 2304 + (QIDX))) * 512 + h * 64 + lane] = f2bf(o);     \
    }

// single-query search pass (used by tails after the joint loop)
#define SEL_PASS(KP, THR, BIT, DONE)                                            \
    {                                                                           \
        const unsigned cand = (THR) | (1u << (BIT));                            \
        const unsigned cm1 = (cand - 1) * 0x10001u;                             \
        unsigned cacc = 0;                                                      \
        _Pragma("unroll")                                                       \
        for (int j = 0; j < 18; ++j) {                                          \
            unsigned s, m;                                                      \
            asm("v_pk_sub_u16 %0, %1, %2 clamp" : "=v"(s) : "v"(KP[j]), "v"(cm1)); \
            asm("v_pk_min_u16 %0, %1, %2" : "=v"(m) : "v"(s), "v"(ones));       \
            cacc += m;                                                          \
        }                                                                       \
        unsigned c = (cacc & 0xFFFFu) + (cacc >> 16);                           \
        _Pragma("unroll")                                                       \
        for (int off = 32; off; off >>= 1) c += (unsigned)__shfl_xor((int)c, off); \
        if (c >= 32) { (THR) = cand; if (c == 32) (DONE) = 1; }                 \
        if (--(BIT) < 0) (DONE) = 1;                                            \
    }

// ---- topk selection: 2 queries/wave (ILP-paired search), 4 waves/block -------
// keys [16][2304][2304] sortable u16, kept PACKED (18 u32/lane per query).
__global__ __launch_bounds__(256)
void k_topk_sel(const u16* __restrict__ keys, const u16* __restrict__ QKV,
                u16* __restrict__ out) {
    __shared__ int      ilist[8][32];
    __shared__ float    wlist[8][32];
    __shared__ unsigned cnt[8];
    const int tid = threadIdx.x, lane = tid & 63, w = tid >> 6;
    const int h = blockIdx.x & 7;
    const int t7 = blockIdx.x >> 3;
    const int b = t7 / 288;
    const int q0 = (t7 % 288) * 8;
    const int qA = q0 + w * 2, qB = qA + 1;
    const int sA = w * 2, sB = sA + 1;

    const u16* krowA = keys + ((size_t)((b * 8 + h) * 2304) + qA) * 2304;
    const u16* krowB = krowA + 2304;
    const ull ltm = (1ull << lane) - 1ull;
    unsigned kpA[18], kpB[18];
#pragma unroll
    for (int j = 0; j < 9; ++j) {
        const uint2 vA = *reinterpret_cast<const uint2*>(krowA + j * 256 + lane * 4);
        const uint2 vB = *reinterpret_cast<const uint2*>(krowB + j * 256 + lane * 4);
        kpA[2 * j] = vA.x; kpA[2 * j + 1] = vA.y;
        kpB[2 * j] = vB.x; kpB[2 * j + 1] = vB.y;
    }
    if (lane == 0) { cnt[sA] = 0u; cnt[sB] = 0u; }

    // ---- brackets (paired): per-lane max, global max, lower bound lo32 ----
    unsigned pmA = kpA[0], pmB = kpB[0];
#pragma unroll
    for (int j = 1; j < 18; ++j) {
        asm("v_pk_max_u16 %0, %1, %2" : "=v"(pmA) : "v"(pmA), "v"(kpA[j]));
        asm("v_pk_max_u16 %0, %1, %2" : "=v"(pmB) : "v"(pmB), "v"(kpB[j]));
    }
    unsigned lmaxA = pmA >> 16, lmaxB = pmB >> 16;
    {
        const unsigned loA = pmA & 0xFFFFu, loB = pmB & 0xFFFFu;
        lmaxA = loA > lmaxA ? loA : lmaxA;
        lmaxB = loB > lmaxB ? loB : lmaxB;
    }
    unsigned m1A = lmaxA, m1B = lmaxB;
#pragma unroll
    for (int off = 32; off; off >>= 1) {
        unsigned oA = (unsigned)__shfl_xor((int)m1A, off);
        unsigned oB = (unsigned)__shfl_xor((int)m1B, off);
        m1A = oA > m1A ? oA : m1A;
        m1B = oB > m1B ? oB : m1B;
    }
    unsigned lo32A = 0, lo32B = 0;
#pragma unroll
    for (int bit = 15; bit >= 0; --bit) {
        const unsigned cA = lo32A | (1u << bit);
        const unsigned cB = lo32B | (1u << bit);
        const int nA = (int)__popcll(__ballot(lmaxA >= cA));
        const int nB = (int)__popcll(__ballot(lmaxB >= cB));
        if (nA >= 32) lo32A = cA;
        if (nB >= 32) lo32B = cB;
    }

    // ---- exact 32nd-largest (paired search below common prefixes) ----
    const unsigned ones = 0x00010001u;
    unsigned thrA, thrB;
    int bitA = -1, bitB = -1, doneA = 0, doneB = 0;
    if (m1A == lo32A) { thrA = m1A; doneA = 1; }
    else {
        const int hb = 31 - __clz(m1A ^ lo32A);
        thrA = m1A & ~((2u << hb) - 1u);
        bitA = hb;
    }
    if (m1B == lo32B) { thrB = m1B; doneB = 1; }
    else {
        const int hb = 31 - __clz(m1B ^ lo32B);
        thrB = m1B & ~((2u << hb) - 1u);
        bitB = hb;
    }
    while (!doneA && !doneB) {
        const unsigned candA = thrA | (1u << bitA);
        const unsigned candB = thrB | (1u << bitB);
        const unsigned cm1A = (candA - 1) * 0x10001u;
        const unsigned cm1B = (candB - 1) * 0x10001u;
        unsigned accA = 0, accB = 0;
#pragma unroll
        for (int j = 0; j < 18; ++j) {
            unsigned sa, ma, sb, mb;
            asm("v_pk_sub_u16 %0, %1, %2 clamp" : "=v"(sa) : "v"(kpA[j]), "v"(cm1A));
            asm("v_pk_sub_u16 %0, %1, %2 clamp" : "=v"(sb) : "v"(kpB[j]), "v"(cm1B));
            asm("v_pk_min_u16 %0, %1, %2" : "=v"(ma) : "v"(sa), "v"(ones));
            asm("v_pk_min_u16 %0, %1, %2" : "=v"(mb) : "v"(sb), "v"(ones));
            accA += ma; accB += mb;
        }
        unsigned cA = (accA & 0xFFFFu) + (accA >> 16);
        unsigned cB = (accB & 0xFFFFu) + (accB >> 16);
#pragma unroll
        for (int off = 32; off; off >>= 1) {
            cA += (unsigned)__shfl_xor((int)cA, off);
            cB += (unsigned)__shfl_xor((int)cB, off);
        }
        if (cA >= 32) { thrA = candA; if (cA == 32) doneA = 1; }
        if (--bitA < 0) doneA = 1;
        if (cB >= 32) { thrB = candB; if (cB == 32) doneB = 1; }
        if (--bitB < 0) doneB = 1;
    }
    while (!doneA) SEL_PASS(kpA, thrA, bitA, doneA);
    while (!doneB) SEL_PASS(kpB, thrB, bitB, doneB);

    // ---- per-query tails ----
    SEL_TAIL(kpA, thrA, qA, sA);
    SEL_TAIL(kpB, thrB, qB, sB);
}

// ---------------- workspace layout (bytes) ---------------
static constexpr size_t O_WQKVC = 0;                       // [1536,768]
static constexpr size_t O_WOC   = O_WQKVC + 2359296;       // [768,512]
static constexpr size_t O_W1C   = O_WOC + 786432;          // [6144,768]
static constexpr size_t O_W2C   = O_W1C + 9437184;         // [768,3072]
static constexpr size_t O_WQKVI = O_W2C + 4718592;         // [1536,512]
static constexpr size_t O_WOI   = O_WQKVI + 1572864;       // [512,512]
static constexpr size_t O_WQX   = O_WOI + 524288;          // [512,512]
static constexpr size_t O_WKVX  = O_WQX + 524288;          // [1024,768]
static constexpr size_t O_WOX   = O_WKVX + 1572864;        // [512,512]
static constexpr size_t O_W1I   = O_WOX + 524288;          // [4096,512]
static constexpr size_t O_W2I   = O_W1I + 4194304;         // [512,2048]
static constexpr size_t O_CF16  = O_W2I + 2097152;         // [512,768] bf16
static constexpr size_t O_H     = O_CF16 + 786432;         // [4608,512] f32
static constexpr size_t O_H2    = O_H + 9437184;           // [4608,512] f32
static constexpr size_t O_S     = O_H2 + 9437184;
// ctx phase
static constexpr size_t O_CN16  = O_S;                     // [512,768] bf16
static constexpr size_t O_QKVC  = O_CN16 + 786432;         // [512,1536] bf16
static constexpr size_t O_VTC   = O_QKVC + 1572864;        // [2,512,256] bf16
static constexpr size_t O_AO16  = O_VTC + 524288;          // [512,512] bf16
static constexpr size_t O_CBUF  = O_AO16 + 524288;         // [512,768] f32
static constexpr size_t O_C16   = O_CBUF + 1572864;        // [512,768] bf16
static constexpr size_t O_AG16  = O_C16 + 786432;          // [512,3072] bf16
// img phase 1
static constexpr size_t O_XLN   = O_S;                     // [4608,512] bf16
static constexpr size_t O_QKVI  = O_XLN + 4718592;         // [4608,1536] bf16
static constexpr size_t O_KEYS  = O_QKVI + 14155776;       // [16,2304,2304] u16
static constexpr size_t O_TO16  = O_KEYS + 169869312;      // [4608,512] bf16
// img phase 2
static constexpr size_t O_H2LN  = O_S;                     // [4608,512] bf16
static constexpr size_t O_XQ    = O_H2LN + 4718592;        // [4608,512] bf16
static constexpr size_t O_KVX   = O_XQ + 4718592;          // [512,1024] bf16
static constexpr size_t O_VTX   = O_KVX + 1048576;         // [2,512,256] bf16
static constexpr size_t O_XO16  = O_VTX + 524288;          // [4608,512] bf16
// ff phase
static constexpr size_t O_H3    = O_S;                     // [4608,512] bf16
static constexpr size_t O_AGI   = O_H3 + 4718592;          // [4608,2048] bf16

extern "C" void kernel_launch(void* const* d_in, const int* in_sizes, int n_in,
                              void* d_out, int out_size, void* d_ws, size_t ws_size,
                              hipStream_t stream) {
    (void)in_sizes; (void)n_in; (void)out_size; (void)ws_size;
    const float* x      = (const float*)d_in[0];
    const float* ctx    = (const float*)d_in[1];
    const float* ctx_wq = (const float*)d_in[3];
    const float* ctx_wk = (const float*)d_in[4];
    const float* ctx_wv = (const float*)d_in[5];
    const float* ctx_wo = (const float*)d_in[6];
    const float* ctx_bo = (const float*)d_in[7];
    const float* cn_g   = (const float*)d_in[8];
    const float* cn_b   = (const float*)d_in[9];
    const float* im_wq  = (const float*)d_in[10];
    const float* im_wk  = (const float*)d_in[11];
    const float* im_wv  = (const float*)d_in[12];
    const float* im_wo  = (const float*)d_in[13];
    const float* im_bo  = (const float*)d_in[14];
    const float* xc_wq  = (const float*)d_in[15];
    const float* xc_wk  = (const float*)d_in[16];
    const float* xc_wv  = (const float*)d_in[17];
    const float* xc_wo  = (const float*)d_in[18];
    const float* xc_bo  = (const float*)d_in[19];
    const float* ffc_w1 = (const float*)d_in[20];
    const float* ffc_b1 = (const float*)d_in[21];
    const float* ffc_w2 = (const float*)d_in[22];
    const float* ffc_b2 = (const float*)d_in[23];
    const float* ffi_w1 = (const float*)d_in[24];
    const float* ffi_b1 = (const float*)d_in[25];
    const float* ffi_w2 = (const float*)d_in[26];
    const float* ffi_b2 = (const float*)d_in[27];
    const float* n1_g   = (const float*)d_in[28];
    const float* n1_b   = (const float*)d_in[29];
    const float* n2_g   = (const float*)d_in[30];
    const float* n2_b   = (const float*)d_in[31];
    const float* n3_g   = (const float*)d_in[32];
    const float* n3_b   = (const float*)d_in[33];
    char* ws = (char*)d_ws;
    float* out = (float*)d_out;
    auto Wp = [&](size_t off) { return (u16*)(ws + off); };
    auto Fp = [&](size_t off) { return (float*)(ws + off); };
    dim3 tb(32, 8);

    // ---- one batched weight transpose+cast (QKV fused along N) ----
    TBatch tbat;
    const float* srcs[16] = {ctx_wq, ctx_wk, ctx_wv, ctx_wo, ffc_w1, ffc_w2,
                             im_wq, im_wk, im_wv, im_wo, xc_wq, xc_wk, xc_wv,
                             xc_wo, ffi_w1, ffi_w2};
    const size_t dsts[16] = {O_WQKVC, O_WQKVC + 786432, O_WQKVC + 1572864, O_WOC,
                             O_W1C, O_W2C,
                             O_WQKVI, O_WQKVI + 524288, O_WQKVI + 1048576, O_WOI,
                             O_WQX, O_WKVX, O_WKVX + 786432, O_WOX,
                             O_W1I, O_W2I};
    const int Ks[16] = {768, 768, 768, 512, 768, 3072, 512, 512, 512, 512,
                        512, 768, 768, 512, 512, 2048};
    const int Ns[16] = {512, 512, 512, 768, 6144, 768, 512, 512, 512, 512,
                        512, 512, 512, 512, 4096, 512};
    int acc = 0;
    for (int i = 0; i < 16; ++i) {
        tbat.src[i] = srcs[i];
        tbat.dst[i] = Wp(dsts[i]);
        tbat.K[i] = Ks[i];
        tbat.N[i] = Ns[i];
        tbat.start[i] = acc;
        acc += (Ns[i] >> 5) * (Ks[i] >> 5);
    }
    tbat.start[16] = acc;
    k_transpose_cast_batch<<<acc, tb, 0, stream>>>(tbat);

    // ---- context path ----
    k_ln_bf16<<<128, 256, 0, stream>>>(ctx, cn_g, cn_b, Wp(O_CN16), 768);
    gemm_bt<64, 64><<<dim3(24, 8), 256, 0, stream>>>(Wp(O_CN16), Wp(O_WQKVC), nullptr, nullptr, nullptr, Wp(O_QKVC), 512, 1536, 768);
    k_vtrans16<<<dim3(16, 8, 2), tb, 0, stream>>>(Wp(O_QKVC), 1536, 1024, Wp(O_VTC));
    k_attn_mfma<<<256, 256, 0, stream>>>(Wp(O_QKVC), 1536, Wp(O_QKVC) + 512, 1536, Wp(O_VTC), Wp(O_AO16), 256);
    gemm_bt<64, 64><<<dim3(12, 8), 256, 0, stream>>>(Wp(O_AO16), Wp(O_WOC), ctx_bo, ctx, Fp(O_CBUF), Wp(O_C16), 512, 768, 512);
    gemm_geglu<64><<<dim3(48, 8), 256, 0, stream>>>(Wp(O_C16), Wp(O_W1C), ffc_b1, Wp(O_AG16), 512, 3072, 768);
    gemm_bt<64, 64><<<dim3(12, 8), 256, 0, stream>>>(Wp(O_AG16), Wp(O_W2C), ffc_b2, Fp(O_CBUF), nullptr, Wp(O_CF16), 512, 768, 3072);

    // ---- image: top-k self-attention (scores GEMM + selection) ----
    k_ln_bf16<<<1152, 256, 0, stream>>>(x, n1_g, n1_b, Wp(O_XLN), 512);
    gemm_bt<64, 64><<<dim3(24, 72), 256, 0, stream>>>(Wp(O_XLN), Wp(O_WQKVI), nullptr, nullptr, nullptr, Wp(O_QKVI), 4608, 1536, 512);
    gemm_scores<<<5184, 256, 0, stream>>>(Wp(O_QKVI), Wp(O_KEYS));
    k_topk_sel<<<4608, 256, 0, stream>>>(Wp(O_KEYS), Wp(O_QKVI), Wp(O_TO16));
    gemm_bt<64, 64><<<dim3(8, 72), 256, 0, stream>>>(Wp(O_TO16), Wp(O_WOI), im_bo, x, Fp(O_H), nullptr, 4608, 512, 512);

    // ---- image -> context cross-attention ----
    k_ln_bf16<<<1152, 256, 0, stream>>>(Fp(O_H), n2_g, n2_b, Wp(O_H2LN), 512);
    gemm_bt<64, 64><<<dim3(8, 72), 256, 0, stream>>>(Wp(O_H2LN), Wp(O_WQX), nullptr, nullptr, nullptr, Wp(O_XQ), 4608, 512, 512);
    gemm_bt<64, 64><<<dim3(16, 8), 256, 0, stream>>>(Wp(O_CF16), Wp(O_WKVX), nullptr, nullptr, nullptr, Wp(O_KVX), 512, 1024, 768);
    k_vtrans16<<<dim3(16, 8, 2), tb, 0, stream>>>(Wp(O_KVX), 1024, 512, Wp(O_VTX));
    k_attn_mfma<<<2304, 256, 0, stream>>>(Wp(O_XQ), 512, Wp(O_KVX), 1024, Wp(O_VTX), Wp(O_XO16), 2304);
    gemm_bt<64, 64><<<dim3(8, 72), 256, 0, stream>>>(Wp(O_XO16), Wp(O_WOX), xc_bo, Fp(O_H), Fp(O_H2), nullptr, 4608, 512, 512);

    // ---- image GEGLU FF ----
    k_ln_bf16<<<1152, 256, 0, stream>>>(Fp(O_H2), n3_g, n3_b, Wp(O_H3), 512);
    gemm_geglu<128><<<dim3(32, 36), 256, 0, stream>>>(Wp(O_H3), Wp(O_W1I), ffi_b1, Wp(O_AGI), 4608, 2048, 512);
    gemm_bt<64, 64><<<dim3(8, 72), 256, 0, stream>>>(Wp(O_AGI), Wp(O_W2I), ffi_b2, Fp(O_H2), out, nullptr, 4608, 512, 2048);
}

// Round 17
// 421.151 us; speedup vs baseline: 1.0297x; 1.0297x over previous
//
#include <hip/hip_runtime.h>
#include <hip/hip_bf16.h>
#include <hip/hip_fp16.h>
#include <cmath>

typedef unsigned short u16;
typedef unsigned long long ull;
typedef __attribute__((ext_vector_type(8))) short short8;
typedef __attribute__((ext_vector_type(4))) float f32x4;
typedef __attribute__((ext_vector_type(4))) unsigned short u16x4;

__device__ __forceinline__ u16 f2bf(float x) {
    unsigned u = __float_as_uint(x);
    u += 0x7fffu + ((u >> 16) & 1u);
    return (u16)(u >> 16);
}
__device__ __forceinline__ float bf2f(u16 b) {
    return __uint_as_float(((unsigned)b) << 16);
}

// sortable-u16 key <-> f16 bits (order-preserving map)
__device__ __forceinline__ unsigned h2key(unsigned hb) {
    return (hb & 0x8000u) ? (hb ^ 0xFFFFu) : (hb | 0x8000u);
}
__device__ __forceinline__ float key2f(unsigned k) {
    unsigned hb = (k & 0x8000u) ? (k ^ 0x8000u) : (k ^ 0xFFFFu);
    return __half2float(__ushort_as_half((unsigned short)hb));
}

// async global->LDS 16B per lane: dest = ldsbase + lane*16 (wave-uniform base)
typedef __attribute__((address_space(3))) unsigned int as3_uint;
typedef __attribute__((address_space(1))) unsigned int as1_uint;
__device__ __forceinline__ void gload_lds16(const u16* g, u16* l) {
    __builtin_amdgcn_global_load_lds(
        (as1_uint*)(unsigned long long)(const void*)g,
        (as3_uint*)(unsigned int)(unsigned long long)(const void*)l,
        16, 0, 0);
}

__device__ __forceinline__ float gelu_exact(float g) {
    return 0.5f * g * (1.f + erff(g * 0.70710678118654752f));
}

// ---------------- batched transpose+cast: w[K][N] f32 -> wt[N][K] bf16 --------
struct TBatch {
    const float* src[16];
    u16* dst[16];
    int K[16];
    int N[16];
    int start[17];
};

__global__ void k_transpose_cast_batch(TBatch tb) {
    __shared__ float tile[32][33];
    int t = blockIdx.x;
    int m = 0;
    while (t >= tb.start[m + 1]) ++m;
    int rel = t - tb.start[m];
    const int K = tb.K[m], N = tb.N[m];
    const int ntx = N >> 5;
    const int n0 = (rel % ntx) * 32, k0 = (rel / ntx) * 32;
    const float* __restrict__ in = tb.src[m];
    u16* __restrict__ out = tb.dst[m];
    int tx = threadIdx.x, ty = threadIdx.y;
#pragma unroll
    for (int j = 0; j < 4; ++j)
        tile[ty + j * 8][tx] = in[(size_t)(k0 + ty + j * 8) * N + n0 + tx];
    __syncthreads();
#pragma unroll
    for (int j = 0; j < 4; ++j)
        out[(size_t)(n0 + ty + j * 8) * K + k0 + tx] = f2bf(tile[tx][ty + j * 8]);
}

// -------- V transpose (bf16 in): in[b*256+k][stride] col coloff+d -> out[b][512][256]
__global__ void k_vtrans16(const u16* __restrict__ in, int stride, int coloff,
                           u16* __restrict__ out) {
    __shared__ int tile[32][33];
    int tx = threadIdx.x, ty = threadIdx.y;
    int d0 = blockIdx.x * 32, k0 = blockIdx.y * 32, b = blockIdx.z;
#pragma unroll
    for (int j = 0; j < 4; ++j)
        tile[ty + j * 8][tx] = in[(size_t)(b * 256 + k0 + ty + j * 8) * stride + coloff + d0 + tx];
    __syncthreads();
#pragma unroll
    for (int j = 0; j < 4; ++j)
        out[(size_t)(b * 512 + d0 + ty + j * 8) * 256 + k0 + tx] = (u16)tile[tx][ty + j * 8];
}

// ---------------- LayerNorm (fp32 in) -> bf16 out; float4-vectorized ----------
__global__ __launch_bounds__(256)
void k_ln_bf16(const float* __restrict__ in, const float* __restrict__ gam,
               const float* __restrict__ bet, u16* __restrict__ out, int F) {
    int lane = threadIdx.x & 63, w = threadIdx.x >> 6;
    int row = blockIdx.x * 4 + w;
    const int F4 = F >> 2;
    const float4* r4 = reinterpret_cast<const float4*>(in + (size_t)row * F);
    const float4* g4 = reinterpret_cast<const float4*>(gam);
    const float4* b4 = reinterpret_cast<const float4*>(bet);
    float s = 0.f, s2 = 0.f;
    for (int j = lane; j < F4; j += 64) {
        float4 v = r4[j];
        s += v.x + v.y + v.z + v.w;
        s2 += v.x * v.x + v.y * v.y + v.z * v.z + v.w * v.w;
    }
#pragma unroll
    for (int off = 32; off; off >>= 1) { s += __shfl_xor(s, off); s2 += __shfl_xor(s2, off); }
    float mean = s / F;
    float var  = s2 / F - mean * mean;
    float inv  = 1.f / sqrtf(var + 1e-5f);
    u16x4* o4 = reinterpret_cast<u16x4*>(out + (size_t)row * F);
    for (int j = lane; j < F4; j += 64) {
        float4 v = r4[j], gm = g4[j], bt = b4[j];
        u16x4 o;
        o[0] = f2bf((v.x - mean) * inv * gm.x + bt.x);
        o[1] = f2bf((v.y - mean) * inv * gm.y + bt.y);
        o[2] = f2bf((v.z - mean) * inv * gm.z + bt.z);
        o[3] = f2bf((v.w - mean) * inv * gm.w + bt.w);
        o4[j] = o;
    }
}

// ------- bf16 MFMA GEMM (templated tile): C[M,N] = A[M,K] @ Bt[N,K]^T ---------
// Chunked XCD swizzle (requires gridDim.x*gridDim.y % 8 == 0).
template <int BM, int BN>
__global__ __launch_bounds__(256)
void gemm_bt(const u16* __restrict__ A, const u16* __restrict__ Bt,
             const float* __restrict__ bias, const float* __restrict__ res,
             float* __restrict__ out32, u16* __restrict__ out16,
             int M, int N, int K) {
    constexpr int WM = BM / 2, WN = BN / 2, FM = WM / 16, FN = WN / 16;
    __shared__ __align__(16) u16 As[BM * 32];
    __shared__ __align__(16) u16 Bs[BN * 32];
    const int tid = threadIdx.x;
    const int lane = tid & 63;
    const int wid = tid >> 6;
    const int wr = wid >> 1, wc = wid & 1;
    const int nwg = gridDim.x * gridDim.y;
    int lin = blockIdx.y * gridDim.x + blockIdx.x;
    lin = (lin & 7) * (nwg >> 3) + (lin >> 3);   // contiguous chunk per XCD
    const int m0 = (lin / gridDim.x) * BM, n0 = (lin % gridDim.x) * BN;
    const int r16 = lane & 15;
    const int g8  = (lane >> 4) * 8;
    const int w16 = wid * 16;
    const int ln4 = lane >> 2;
    const int cb8 = (lane & 3) * 8;

    const f32x4 zero4 = {0.f, 0.f, 0.f, 0.f};
    f32x4 acc[FM][FN];
#pragma unroll
    for (int m = 0; m < FM; ++m)
#pragma unroll
        for (int n = 0; n < FN; ++n) acc[m][n] = zero4;

    for (int k0 = 0; k0 < K; k0 += 32) {
#pragma unroll
        for (int p = 0; p < BM / 64; ++p) {
            const int rb = p * 64 + w16;
            gload_lds16(A + (size_t)(m0 + rb + ln4) * K + k0 + cb8, &As[rb * 32]);
        }
#pragma unroll
        for (int p = 0; p < BN / 64; ++p) {
            const int rb = p * 64 + w16;
            gload_lds16(Bt + (size_t)(n0 + rb + ln4) * K + k0 + cb8, &Bs[rb * 32]);
        }
        __syncthreads();
        short8 af[FM], bfr[FN];
#pragma unroll
        for (int m = 0; m < FM; ++m)
            af[m] = *reinterpret_cast<const short8*>(&As[(wr * WM + m * 16 + r16) * 32 + g8]);
#pragma unroll
        for (int n = 0; n < FN; ++n)
            bfr[n] = *reinterpret_cast<const short8*>(&Bs[(wc * WN + n * 16 + r16) * 32 + g8]);
#pragma unroll
        for (int m = 0; m < FM; ++m)
#pragma unroll
            for (int n = 0; n < FN; ++n)
                acc[m][n] = __builtin_amdgcn_mfma_f32_16x16x32_bf16(af[m], bfr[n], acc[m][n], 0, 0, 0);
        __syncthreads();
    }

    const int rg = (lane >> 4) * 4;
#pragma unroll
    for (int m = 0; m < FM; ++m) {
#pragma unroll
        for (int n = 0; n < FN; ++n) {
#pragma unroll
            for (int j = 0; j < 4; ++j) {
                int row = m0 + wr * WM + m * 16 + rg + j;
                int col = n0 + wc * WN + n * 16 + r16;
                float v = acc[m][n][j];
                if (bias) v += bias[col];
                size_t off = (size_t)row * N + col;
                if (res) v += res[off];
                if (out32) out32[off] = v;
                if (out16) out16[off] = f2bf(v);
            }
        }
    }
}

// ---- GEGLU-fused GEMM: out[M,Nh] = (A@Wa^T + ba) * gelu(A@Wg^T + bg) ---------
template <int BM>
__global__ __launch_bounds__(256)
void gemm_geglu(const u16* __restrict__ A, const u16* __restrict__ Bt,
                const float* __restrict__ bias, u16* __restrict__ out16,
                int M, int Nh, int K) {
    constexpr int WM = BM / 2, FM = WM / 16;
    __shared__ __align__(16) u16 As[BM * 32];
    __shared__ __align__(16) u16 Bs[128 * 32];
    const int tid = threadIdx.x;
    const int lane = tid & 63;
    const int wid = tid >> 6;
    const int wr = wid >> 1, wc = wid & 1;
    const int nwg = gridDim.x * gridDim.y;
    int lin = blockIdx.y * gridDim.x + blockIdx.x;
    lin = (lin & 7) * (nwg >> 3) + (lin >> 3);
    const int m0 = (lin / gridDim.x) * BM, n0 = (lin % gridDim.x) * 64;
    const int r16 = lane & 15;
    const int g8  = (lane >> 4) * 8;
    const int w16 = wid * 16;
    const int ln4 = lane >> 2;
    const int cb8 = (lane & 3) * 8;

    const f32x4 zero4 = {0.f, 0.f, 0.f, 0.f};
    f32x4 acc_a[FM][2], acc_g[FM][2];
#pragma unroll
    for (int m = 0; m < FM; ++m)
#pragma unroll
        for (int n = 0; n < 2; ++n) { acc_a[m][n] = zero4; acc_g[m][n] = zero4; }

    for (int k0 = 0; k0 < K; k0 += 32) {
#pragma unroll
        for (int p = 0; p < BM / 64; ++p) {
            const int rb = p * 64 + w16;
            gload_lds16(A + (size_t)(m0 + rb + ln4) * K + k0 + cb8, &As[rb * 32]);
        }
        gload_lds16(Bt + (size_t)(n0 + w16 + ln4) * K + k0 + cb8, &Bs[w16 * 32]);
        gload_lds16(Bt + (size_t)(Nh + n0 + w16 + ln4) * K + k0 + cb8, &Bs[(64 + w16) * 32]);
        __syncthreads();
        short8 af[FM], ba[2], bg[2];
#pragma unroll
        for (int m = 0; m < FM; ++m)
            af[m] = *reinterpret_cast<const short8*>(&As[(wr * WM + m * 16 + r16) * 32 + g8]);
#pragma unroll
        for (int n = 0; n < 2; ++n) {
            ba[n] = *reinterpret_cast<const short8*>(&Bs[(wc * 32 + n * 16 + r16) * 32 + g8]);
            bg[n] = *reinterpret_cast<const short8*>(&Bs[(64 + wc * 32 + n * 16 + r16) * 32 + g8]);
        }
#pragma unroll
        for (int m = 0; m < FM; ++m)
#pragma unroll
            for (int n = 0; n < 2; ++n) {
                acc_a[m][n] = __builtin_amdgcn_mfma_f32_16x16x32_bf16(af[m], ba[n], acc_a[m][n], 0, 0, 0);
                acc_g[m][n] = __builtin_amdgcn_mfma_f32_16x16x32_bf16(af[m], bg[n], acc_g[m][n], 0, 0, 0);
            }
        __syncthreads();
    }

    const int rg = (lane >> 4) * 4;
#pragma unroll
    for (int m = 0; m < FM; ++m) {
#pragma unroll
        for (int n = 0; n < 2; ++n) {
#pragma unroll
            for (int j = 0; j < 4; ++j) {
                int row = m0 + wr * WM + m * 16 + rg + j;
                int col = n0 + wc * 32 + n * 16 + r16;
                float a = acc_a[m][n][j] + bias[col];
                float g = acc_g[m][n][j] + bias[Nh + col];
                out16[(size_t)row * Nh + col] = f2bf(a * gelu_exact(g));
            }
        }
    }
}

// ---------------- MFMA SDPA attention, 256 keys, 8 heads, dh=64 ----------------
// XCD swizzle: h = bid&7 pins each head's K/V panel to one XCD L2.
__global__ __launch_bounds__(256)
void k_attn_mfma(const u16* __restrict__ Qb, int sq, const u16* __restrict__ Kb,
                 int sk, const u16* __restrict__ VT, u16* __restrict__ out, int NQ) {
    __shared__ float sc[16][268];
    __shared__ u16   pb[16][268];
    const int tid = threadIdx.x, lane = tid & 63, w = tid >> 6;
    const int nqb = NQ >> 4;
    const int h = blockIdx.x & 7;
    const int rest = blockIdx.x >> 3;
    const int b = rest / nqb;
    const int q0 = (rest % nqb) << 4;
    const int r16 = lane & 15, g8 = (lane >> 4) * 8, rq = (lane >> 4) * 4;

    const size_t qrow = ((size_t)(b * NQ + q0 + r16)) * sq + h * 64;
    const short8 af0 = *reinterpret_cast<const short8*>(Qb + qrow + g8);
    const short8 af1 = *reinterpret_cast<const short8*>(Qb + qrow + 32 + g8);
    const u16* kb = Kb + (size_t)b * 256 * sk + h * 64;
    const f32x4 zero4 = {0.f, 0.f, 0.f, 0.f};
#pragma unroll
    for (int t = 0; t < 4; ++t) {
        const size_t krow = (size_t)(t * 64 + w * 16 + r16) * sk;
        const short8 bf0 = *reinterpret_cast<const short8*>(kb + krow + g8);
        const short8 bf1 = *reinterpret_cast<const short8*>(kb + krow + 32 + g8);
        f32x4 acc = __builtin_amdgcn_mfma_f32_16x16x32_bf16(af0, bf0, zero4, 0, 0, 0);
        acc = __builtin_amdgcn_mfma_f32_16x16x32_bf16(af1, bf1, acc, 0, 0, 0);
        const int col = t * 64 + w * 16 + r16;
#pragma unroll
        for (int j = 0; j < 4; ++j) sc[rq + j][col] = acc[j] * 0.125f;
    }
    __syncthreads();
#pragma unroll
    for (int qi = 0; qi < 4; ++qi) {
        const int q = w * 4 + qi;
        float4 v = *reinterpret_cast<const float4*>(&sc[q][lane * 4]);
        float m = fmaxf(fmaxf(v.x, v.y), fmaxf(v.z, v.w));
#pragma unroll
        for (int off = 32; off; off >>= 1) m = fmaxf(m, __shfl_xor(m, off));
        float e0 = expf(v.x - m), e1 = expf(v.y - m), e2 = expf(v.z - m), e3 = expf(v.w - m);
        float sum = e0 + e1 + e2 + e3;
#pragma unroll
        for (int off = 32; off; off >>= 1) sum += __shfl_xor(sum, off);
        float inv = 1.f / sum;
        u16x4 p4;
        p4[0] = f2bf(e0 * inv); p4[1] = f2bf(e1 * inv);
        p4[2] = f2bf(e2 * inv); p4[3] = f2bf(e3 * inv);
        *reinterpret_cast<u16x4*>(&pb[q][lane * 4]) = p4;
    }
    __syncthreads();
    f32x4 o = zero4;
    const u16* vt = VT + ((size_t)(b * 512 + h * 64 + w * 16 + r16)) * 256;
#pragma unroll
    for (int kk = 0; kk < 8; ++kk) {
        const short8 pa = *reinterpret_cast<const short8*>(&pb[r16][kk * 32 + g8]);
        const short8 vv = *reinterpret_cast<const short8*>(vt + kk * 32 + g8);
        o = __builtin_amdgcn_mfma_f32_16x16x32_bf16(pa, vv, o, 0, 0, 0);
    }
#pragma unroll
    for (int j = 0; j < 4; ++j)
        out[((size_t)(b * NQ + q0 + rq + j)) * 512 + h * 64 + w * 16 + r16] = f2bf(o[j]);
}

// ---- topk scores GEMM: keys[bh][q][k] = sortable_u16(f16(QK^T * 0.125)) ------
__global__ __launch_bounds__(256)
void gemm_scores(const u16* __restrict__ QKV, u16* __restrict__ keys) {
    __shared__ __align__(16) u16 As[2][128 * 32];
    __shared__ __align__(16) u16 Bs[2][128 * 32];
    const int tid = threadIdx.x;
    const int lane = tid & 63;
    const int wid = tid >> 6;
    const int wr = wid >> 1, wc = wid & 1;
    int lin = blockIdx.x;                       // 5184 = 16 * 324
    lin = (lin & 7) * 648 + (lin >> 3);
    const int bh = lin / 324;
    const int rel = lin % 324;
    const int m0 = (rel / 18) * 128, n0 = (rel % 18) * 128;
    const int b = bh >> 3, h = bh & 7;
    const u16* Qb = QKV + (size_t)b * 2304 * 1536 + h * 64;   // rows stride 1536
    const u16* Kb = Qb + 512;
    const int r16 = lane & 15;
    const int g8  = (lane >> 4) * 8;
    const int w16 = wid * 16;
    const int ln4 = lane >> 2;
    const int cb8 = (lane & 3) * 8;

#pragma unroll
    for (int kk = 0; kk < 2; ++kk) {
#pragma unroll
        for (int p = 0; p < 2; ++p) {
            const int rb = p * 64 + w16;
            gload_lds16(Qb + (size_t)(m0 + rb + ln4) * 1536 + kk * 32 + cb8, &As[kk][rb * 32]);
            gload_lds16(Kb + (size_t)(n0 + rb + ln4) * 1536 + kk * 32 + cb8, &Bs[kk][rb * 32]);
        }
    }
    __syncthreads();

    const f32x4 zero4 = {0.f, 0.f, 0.f, 0.f};
    f32x4 acc[4][4];
#pragma unroll
    for (int m = 0; m < 4; ++m)
#pragma unroll
        for (int n = 0; n < 4; ++n) acc[m][n] = zero4;

    short8 af[2][4], bfr[2][4];
#pragma unroll
    for (int kk = 0; kk < 2; ++kk)
#pragma unroll
        for (int m = 0; m < 4; ++m) {
            af[kk][m] = *reinterpret_cast<const short8*>(&As[kk][(wr * 64 + m * 16 + r16) * 32 + g8]);
            bfr[kk][m] = *reinterpret_cast<const short8*>(&Bs[kk][(wc * 64 + m * 16 + r16) * 32 + g8]);
        }
#pragma unroll
    for (int kk = 0; kk < 2; ++kk)
#pragma unroll
        for (int m = 0; m < 4; ++m)
#pragma unroll
            for (int n = 0; n < 4; ++n)
                acc[m][n] = __builtin_amdgcn_mfma_f32_16x16x32_bf16(af[kk][m], bfr[kk][n], acc[m][n], 0, 0, 0);

    u16* kout = keys + (size_t)bh * 2304 * 2304;
    const int rg = (lane >> 4) * 4;
#pragma unroll
    for (int m = 0; m < 4; ++m) {
#pragma unroll
        for (int n = 0; n < 4; ++n) {
#pragma unroll
            for (int j = 0; j < 4; ++j) {
                int row = m0 + wr * 64 + m * 16 + rg + j;
                int col = n0 + wc * 64 + n * 16 + r16;
                unsigned hb = __half_as_ushort(__float2half(acc[m][n][j] * 0.125f));
                kout[(size_t)row * 2304 + col] = (u16)h2key(hb);
            }
        }
    }
}

// ---- topk selection: 1 query/wave, 4/block; bracketed packed-u16 search ------
// keys [16][2304][2304] sortable u16, kept PACKED (18 u32/lane).
// reg i: lo half -> g = (i>>1)*256 + lane*4 + (i&1)*2, hi half -> g+1.
// Bracket: lo32 = 32nd-largest of the 64 per-lane maxima (valid lower bound),
// m1 = global max (upper bound). thr shares their common binary prefix ->
// search only the differing low bits.
__global__ __launch_bounds__(256)
void k_topk_sel(const u16* __restrict__ keys, const u16* __restrict__ QKV,
                u16* __restrict__ out) {
    __shared__ int      ilist[4][32];
    __shared__ float    wlist[4][32];
    __shared__ unsigned cnt[4];
    const int tid = threadIdx.x, lane = tid & 63, w = tid >> 6;
    const int h = blockIdx.x & 7;
    const int t7 = blockIdx.x >> 3;
    const int b = t7 / 576;
    const int q = (t7 % 576) * 4 + w;

    const u16* krow = keys + ((size_t)((b * 8 + h) * 2304) + q) * 2304;
    const ull ltm = (1ull << lane) - 1ull;
    unsigned kp[18];
#pragma unroll
    for (int j = 0; j < 9; ++j) {
        const uint2 v = *reinterpret_cast<const uint2*>(krow + j * 256 + lane * 4);
        kp[2 * j] = v.x; kp[2 * j + 1] = v.y;
    }
    if (lane == 0) cnt[w] = 0u;

    // ---- bracket: per-lane max, global max m1, lower bound lo32 ----
    unsigned pm = kp[0];
#pragma unroll
    for (int j = 1; j < 18; ++j)
        asm("v_pk_max_u16 %0, %1, %2" : "=v"(pm) : "v"(pm), "v"(kp[j]));
    unsigned lmax = pm >> 16;
    {
        const unsigned lo16 = pm & 0xFFFFu;
        lmax = lo16 > lmax ? lo16 : lmax;
    }
    unsigned m1 = lmax;
#pragma unroll
    for (int off = 32; off; off >>= 1) {
        unsigned o = (unsigned)__shfl_xor((int)m1, off);
        m1 = o > m1 ? o : m1;
    }
    unsigned lo32 = 0;
#pragma unroll
    for (int bit = 15; bit >= 0; --bit) {
        const unsigned cand = lo32 | (1u << bit);
        if ((int)__popcll(__ballot(lmax >= cand)) >= 32) lo32 = cand;
    }

    // ---- exact 32nd-largest: search only bits below the common prefix ----
    unsigned thr;
    if (m1 == lo32) {
        thr = m1;
    } else {
        const unsigned diff = m1 ^ lo32;
        const int hb = 31 - __clz(diff);          // 0..15, wave-uniform
        thr = m1 & ~((2u << hb) - 1u);            // common prefix, low bits 0
        const unsigned ones = 0x00010001u;
        for (int bit = hb; bit >= 0; --bit) {
            const unsigned cand = thr | (1u << bit);
            const unsigned cm1 = (cand - 1) * 0x10001u;
            unsigned cacc = 0;
#pragma unroll
            for (int j = 0; j < 18; ++j) {
                unsigned s, m;
                asm("v_pk_sub_u16 %0, %1, %2 clamp" : "=v"(s) : "v"(kp[j]), "v"(cm1));
                asm("v_pk_min_u16 %0, %1, %2" : "=v"(m) : "v"(s), "v"(ones));
                cacc += m;   // halves stay <= 18: no cross-half carry
            }
            unsigned c = (cacc & 0xFFFFu) + (cacc >> 16);
#pragma unroll
            for (int off = 32; off; off >>= 1) c += (unsigned)__shfl_xor((int)c, off);
            if (c >= 32) { thr = cand; if (c == 32) break; }
        }
    }

    // strict pass: keys > thr, order-free LDS atomic append (count <= 31)
    const unsigned tp = thr * 0x10001u;
#pragma unroll
    for (int i = 0; i < 18; ++i) {
        unsigned s;
        asm("v_pk_sub_u16 %0, %1, %2 clamp" : "=v"(s) : "v"(kp[i]), "v"(tp));
        if (s) {
            const unsigned klo = kp[i] & 0xFFFFu, khi = kp[i] >> 16;
            const int gbase = (i >> 1) * 256 + lane * 4 + (i & 1) * 2;
            if (klo > thr) {
                unsigned pos = atomicAdd(&cnt[w], 1u);
                ilist[w][pos] = gbase; wlist[w][pos] = key2f(klo);
            }
            if (khi > thr) {
                unsigned pos = atomicAdd(&cnt[w], 1u);
                ilist[w][pos] = gbase + 1; wlist[w][pos] = key2f(khi);
            }
        }
    }
    const int tot = (int)cnt[w];
    // tie pass: keys == thr, ascending global index; skip once r ties scanned
    const int r = 32 - tot;
    if (r > 0) {
        const float tv = key2f(thr);
        int t2 = 0;
#pragma unroll
        for (int j = 0; j < 9; ++j) {
            if (t2 < r) {
                const unsigned x = kp[2 * j], y = kp[2 * j + 1];
                const unsigned ka = x & 0xFFFFu, kb = x >> 16;
                const unsigned kc = y & 0xFFFFu, kd = y >> 16;
                const ull m0 = __ballot(ka == thr);
                const ull m1b = __ballot(kb == thr);
                const ull m2 = __ballot(kc == thr);
                const ull m3 = __ballot(kd == thr);
                const int base = (int)__popcll(m0 & ltm) + (int)__popcll(m1b & ltm) +
                                 (int)__popcll(m2 & ltm) + (int)__popcll(m3 & ltm);
                const int b0 = (int)((m0 >> lane) & 1ull);
                const int b1 = b0 + (int)((m1b >> lane) & 1ull);
                const int b2 = b1 + (int)((m2 >> lane) & 1ull);
                if (ka == thr) {
                    int pos = t2 + base;
                    if (pos < r) { ilist[w][tot + pos] = j * 256 + lane * 4 + 0; wlist[w][tot + pos] = tv; }
                }
                if (kb == thr) {
                    int pos = t2 + base + b0;
                    if (pos < r) { ilist[w][tot + pos] = j * 256 + lane * 4 + 1; wlist[w][tot + pos] = tv; }
                }
                if (kc == thr) {
                    int pos = t2 + base + b1;
                    if (pos < r) { ilist[w][tot + pos] = j * 256 + lane * 4 + 2; wlist[w][tot + pos] = tv; }
                }
                if (kd == thr) {
                    int pos = t2 + base + b2;
                    if (pos < r) { ilist[w][tot + pos] = j * 256 + lane * 4 + 3; wlist[w][tot + pos] = tv; }
                }
                t2 += (int)__popcll(m0) + (int)__popcll(m1b) +
                      (int)__popcll(m2) + (int)__popcll(m3);
            }
        }
    }
    // softmax over the 32 selected; max taken from the selected values
    float wv = (lane < 32) ? wlist[w][lane] : -3.0e38f;
    float mf = wv;
#pragma unroll
    for (int off = 32; off; off >>= 1) mf = fmaxf(mf, __shfl_xor(mf, off));
    float e = (lane < 32) ? expf(wv - mf) : 0.f;
    float sum = e;
#pragma unroll
    for (int off = 32; off; off >>= 1) sum += __shfl_xor(sum, off);
    if (lane < 32) wlist[w][lane] = e / sum;
    // PV gather: batch all 32 row loads, then reduce
    const u16* vb = QKV + (size_t)b * 2304 * 1536 + 1024 + h * 64 + lane;
    u16 vr[32];
#pragma unroll
    for (int i = 0; i < 32; ++i)
        vr[i] = vb[(size_t)ilist[w][i] * 1536];
    float o = 0.f;
#pragma unroll
    for (int i = 0; i < 32; ++i)
        o += wlist[w][i] * bf2f(vr[i]);
    out[((size_t)(b * 2304 + q)) * 512 + h * 64 + lane] = f2bf(o);
}

// ---------------- workspace layout (bytes) ---------------
static constexpr size_t O_WQKVC = 0;                       // [1536,768]
static constexpr size_t O_WOC   = O_WQKVC + 2359296;       // [768,512]
static constexpr size_t O_W1C   = O_WOC + 786432;          // [6144,768]
static constexpr size_t O_W2C   = O_W1C + 9437184;         // [768,3072]
static constexpr size_t O_WQKVI = O_W2C + 4718592;         // [1536,512]
static constexpr size_t O_WOI   = O_WQKVI + 1572864;       // [512,512]
static constexpr size_t O_WQX   = O_WOI + 524288;          // [512,512]
static constexpr size_t O_WKVX  = O_WQX + 524288;          // [1024,768]
static constexpr size_t O_WOX   = O_WKVX + 1572864;        // [512,512]
static constexpr size_t O_W1I   = O_WOX + 524288;          // [4096,512]
static constexpr size_t O_W2I   = O_W1I + 4194304;         // [512,2048]
static constexpr size_t O_CF16  = O_W2I + 2097152;         // [512,768] bf16
static constexpr size_t O_H     = O_CF16 + 786432;         // [4608,512] f32
static constexpr size_t O_H2    = O_H + 9437184;           // [4608,512] f32
static constexpr size_t O_S     = O_H2 + 9437184;
// ctx phase
static constexpr size_t O_CN16  = O_S;                     // [512,768] bf16
static constexpr size_t O_QKVC  = O_CN16 + 786432;         // [512,1536] bf16
static constexpr size_t O_VTC   = O_QKVC + 1572864;        // [2,512,256] bf16
static constexpr size_t O_AO16  = O_VTC + 524288;          // [512,512] bf16
static constexpr size_t O_CBUF  = O_AO16 + 524288;         // [512,768] f32
static constexpr size_t O_C16   = O_CBUF + 1572864;        // [512,768] bf16
static constexpr size_t O_AG16  = O_C16 + 786432;          // [512,3072] bf16
// img phase 1
static constexpr size_t O_XLN   = O_S;                     // [4608,512] bf16
static constexpr size_t O_QKVI  = O_XLN + 4718592;         // [4608,1536] bf16
static constexpr size_t O_KEYS  = O_QKVI + 14155776;       // [16,2304,2304] u16
static constexpr size_t O_TO16  = O_KEYS + 169869312;      // [4608,512] bf16
// img phase 2
static constexpr size_t O_H2LN  = O_S;                     // [4608,512] bf16
static constexpr size_t O_XQ    = O_H2LN + 4718592;        // [4608,512] bf16
static constexpr size_t O_KVX   = O_XQ + 4718592;          // [512,1024] bf16
static constexpr size_t O_VTX   = O_KVX + 1048576;         // [2,512,256] bf16
static constexpr size_t O_XO16  = O_VTX + 524288;          // [4608,512] bf16
// ff phase
static constexpr size_t O_H3    = O_S;                     // [4608,512] bf16
static constexpr size_t O_AGI   = O_H3 + 4718592;          // [4608,2048] bf16

extern "C" void kernel_launch(void* const* d_in, const int* in_sizes, int n_in,
                              void* d_out, int out_size, void* d_ws, size_t ws_size,
                              hipStream_t stream) {
    (void)in_sizes; (void)n_in; (void)out_size; (void)ws_size;
    const float* x      = (const float*)d_in[0];
    const float* ctx    = (const float*)d_in[1];
    const float* ctx_wq = (const float*)d_in[3];
    const float* ctx_wk = (const float*)d_in[4];
    const float* ctx_wv = (const float*)d_in[5];
    const float* ctx_wo = (const float*)d_in[6];
    const float* ctx_bo = (const float*)d_in[7];
    const float* cn_g   = (const float*)d_in[8];
    const float* cn_b   = (const float*)d_in[9];
    const float* im_wq  = (const float*)d_in[10];
    const float* im_wk  = (const float*)d_in[11];
    const float* im_wv  = (const float*)d_in[12];
    const float* im_wo  = (const float*)d_in[13];
    const float* im_bo  = (const float*)d_in[14];
    const float* xc_wq  = (const float*)d_in[15];
    const float* xc_wk  = (const float*)d_in[16];
    const float* xc_wv  = (const float*)d_in[17];
    const float* xc_wo  = (const float*)d_in[18];
    const float* xc_bo  = (const float*)d_in[19];
    const float* ffc_w1 = (const float*)d_in[20];
    const float* ffc_b1 = (const float*)d_in[21];
    const float* ffc_w2 = (const float*)d_in[22];
    const float* ffc_b2 = (const float*)d_in[23];
    const float* ffi_w1 = (const float*)d_in[24];
    const float* ffi_b1 = (const float*)d_in[25];
    const float* ffi_w2 = (const float*)d_in[26];
    const float* ffi_b2 = (const float*)d_in[27];
    const float* n1_g   = (const float*)d_in[28];
    const float* n1_b   = (const float*)d_in[29];
    const float* n2_g   = (const float*)d_in[30];
    const float* n2_b   = (const float*)d_in[31];
    const float* n3_g   = (const float*)d_in[32];
    const float* n3_b   = (const float*)d_in[33];
    char* ws = (char*)d_ws;
    float* out = (float*)d_out;
    auto Wp = [&](size_t off) { return (u16*)(ws + off); };
    auto Fp = [&](size_t off) { return (float*)(ws + off); };
    dim3 tb(32, 8);

    // ---- one batched weight transpose+cast (QKV fused along N) ----
    TBatch tbat;
    const float* srcs[16] = {ctx_wq, ctx_wk, ctx_wv, ctx_wo, ffc_w1, ffc_w2,
                             im_wq, im_wk, im_wv, im_wo, xc_wq, xc_wk, xc_wv,
                             xc_wo, ffi_w1, ffi_w2};
    const size_t dsts[16] = {O_WQKVC, O_WQKVC + 786432, O_WQKVC + 1572864, O_WOC,
                             O_W1C, O_W2C,
                             O_WQKVI, O_WQKVI + 524288, O_WQKVI + 1048576, O_WOI,
                             O_WQX, O_WKVX, O_WKVX + 786432, O_WOX,
                             O_W1I, O_W2I};
    const int Ks[16] = {768, 768, 768, 512, 768, 3072, 512, 512, 512, 512,
                        512, 768, 768, 512, 512, 2048};
    const int Ns[16] = {512, 512, 512, 768, 6144, 768, 512, 512, 512, 512,
                        512, 512, 512, 512, 4096, 512};
    int acc = 0;
    for (int i = 0; i < 16; ++i) {
        tbat.src[i] = srcs[i];
        tbat.dst[i] = Wp(dsts[i]);
        tbat.K[i] = Ks[i];
        tbat.N[i] = Ns[i];
        tbat.start[i] = acc;
        acc += (Ns[i] >> 5) * (Ks[i] >> 5);
    }
    tbat.start[16] = acc;
    k_transpose_cast_batch<<<acc, tb, 0, stream>>>(tbat);

    // ---- context path ----
    k_ln_bf16<<<128, 256, 0, stream>>>(ctx, cn_g, cn_b, Wp(O_CN16), 768);
    gemm_bt<64, 64><<<dim3(24, 8), 256, 0, stream>>>(Wp(O_CN16), Wp(O_WQKVC), nullptr, nullptr, nullptr, Wp(O_QKVC), 512, 1536, 768);
    k_vtrans16<<<dim3(16, 8, 2), tb, 0, stream>>>(Wp(O_QKVC), 1536, 1024, Wp(O_VTC));
    k_attn_mfma<<<256, 256, 0, stream>>>(Wp(O_QKVC), 1536, Wp(O_QKVC) + 512, 1536, Wp(O_VTC), Wp(O_AO16), 256);
    gemm_bt<64, 64><<<dim3(12, 8), 256, 0, stream>>>(Wp(O_AO16), Wp(O_WOC), ctx_bo, ctx, Fp(O_CBUF), Wp(O_C16), 512, 768, 512);
    gemm_geglu<64><<<dim3(48, 8), 256, 0, stream>>>(Wp(O_C16), Wp(O_W1C), ffc_b1, Wp(O_AG16), 512, 3072, 768);
    gemm_bt<64, 64><<<dim3(12, 8), 256, 0, stream>>>(Wp(O_AG16), Wp(O_W2C), ffc_b2, Fp(O_CBUF), nullptr, Wp(O_CF16), 512, 768, 3072);

    // ---- image: top-k self-attention (scores GEMM + selection) ----
    k_ln_bf16<<<1152, 256, 0, stream>>>(x, n1_g, n1_b, Wp(O_XLN), 512);
    gemm_bt<64, 64><<<dim3(24, 72), 256, 0, stream>>>(Wp(O_XLN), Wp(O_WQKVI), nullptr, nullptr, nullptr, Wp(O_QKVI), 4608, 1536, 512);
    gemm_scores<<<5184, 256, 0, stream>>>(Wp(O_QKVI), Wp(O_KEYS));
    k_topk_sel<<<9216, 256, 0, stream>>>(Wp(O_KEYS), Wp(O_QKVI), Wp(O_TO16));
    gemm_bt<64, 64><<<dim3(8, 72), 256, 0, stream>>>(Wp(O_TO16), Wp(O_WOI), im_bo, x, Fp(O_H), nullptr, 4608, 512, 512);

    // ---- image -> context cross-attention ----
    k_ln_bf16<<<1152, 256, 0, stream>>>(Fp(O_H), n2_g, n2_b, Wp(O_H2LN), 512);
    gemm_bt<64, 64><<<dim3(8, 72), 256, 0, stream>>>(Wp(O_H2LN), Wp(O_WQX), nullptr, nullptr, nullptr, Wp(O_XQ), 4608, 512, 512);
    gemm_bt<64, 64><<<dim3(16, 8), 256, 0, stream>>>(Wp(O_CF16), Wp(O_WKVX), nullptr, nullptr, nullptr, Wp(O_KVX), 512, 1024, 768);
    k_vtrans16<<<dim3(16, 8, 2), tb, 0, stream>>>(Wp(O_KVX), 1024, 512, Wp(O_VTX));
    k_attn_mfma<<<2304, 256, 0, stream>>>(Wp(O_XQ), 512, Wp(O_KVX), 1024, Wp(O_VTX), Wp(O_XO16), 2304);
    gemm_bt<64, 64><<<dim3(8, 72), 256, 0, stream>>>(Wp(O_XO16), Wp(O_WOX), xc_bo, Fp(O_H), Fp(O_H2), nullptr, 4608, 512, 512);

    // ---- image GEGLU FF ----
    k_ln_bf16<<<1152, 256, 0, stream>>>(Fp(O_H2), n3_g, n3_b, Wp(O_H3), 512);
    gemm_geglu<128><<<dim3(32, 36), 256, 0, stream>>>(Wp(O_H3), Wp(O_W1I), ffi_b1, Wp(O_AGI), 4608, 2048, 512);
    gemm_bt<64, 64><<<dim3(8, 72), 256, 0, stream>>>(Wp(O_AGI), Wp(O_W2I), ffi_b2, Fp(O_H2), out, nullptr, 4608, 512, 2048);
}